// Round 16
// baseline (43.311 us; speedup 1.0000x reference)
//
#include <hip/hip_runtime.h>
#include <math.h>

#define KDIM 32
#define MDIM 256
#define NDIM 2048
#define W_TOL 1e-3f   // base add threshold (hysteresis; solution shift <= W_TOL/lambda_min ~ 1e-5)

// ---------------- helpers ----------------
__device__ __forceinline__ float lane_bcast(float x, int lane) {
  return __int_as_float(__builtin_amdgcn_readlane(__float_as_int(x), lane));
}
__device__ __forceinline__ float rcp_newton(float x) {
  float r;
  asm("v_rcp_f32 %0, %1" : "=v"(r) : "v"(x));
  r = r * (2.0f - x * r);  // one Newton step (shared inverse only)
  return r;
}
__device__ __forceinline__ float rcp_fast(float x) {
  float r;
  asm("v_rcp_f32 %0, %1" : "=v"(r) : "v"(x));
  return r;  // ~1 ulp; fine vs 3e-3 threshold (kappa ~ 56 both modes)
}

// ---------------- prep: AtXt (blocks 0..63) + AtA & inverse (block 64) ---------
// A-row operands are read DIRECTLY from global: identical addresses across
// lanes collapse to one L2 transaction (A = 32KB, L2-hot), keeping the LDS
// pipe free. LDS used only for the AtXt cross-chunk reduce and padded AtAs.
__global__ __launch_bounds__(256) void prep_kernel(const float* __restrict__ A,
                                                   const float* __restrict__ X,
                                                   float* __restrict__ AtA,
                                                   float* __restrict__ Ainv,
                                                   float* __restrict__ AtXt) {
  __shared__ float buf[8448];  // reduce scratch [8][32][33] / padded AtAs
  const int t = threadIdx.x;

  if (blockIdx.x < 64) {
    // ---- AtXt[n][k] for 32 columns; 8-way m-split across 256 threads ----
    const int nl = t & 31;     // column within block
    const int ch = t >> 5;     // m-chunk 0..7
    const int n = blockIdx.x * 32 + nl;
    float acc[KDIM];
#pragma unroll
    for (int k = 0; k < KDIM; ++k) acc[k] = 0.f;
#pragma unroll 4
    for (int mm = 0; mm < 32; ++mm) {
      const int m = ch * 32 + mm;
      const float x = X[m * NDIM + n];  // 2 coalesced 128B segments per instr
      const float4* Arow = reinterpret_cast<const float4*>(A + m * KDIM);
#pragma unroll
      for (int qq = 0; qq < 8; ++qq) {
        const float4 a4 = Arow[qq];  // wave-broadcast addr -> 1 L2 transaction
        acc[4 * qq + 0] = fmaf(a4.x, x, acc[4 * qq + 0]);
        acc[4 * qq + 1] = fmaf(a4.y, x, acc[4 * qq + 1]);
        acc[4 * qq + 2] = fmaf(a4.z, x, acc[4 * qq + 2]);
        acc[4 * qq + 3] = fmaf(a4.w, x, acc[4 * qq + 3]);
      }
    }
#pragma unroll
    for (int k = 0; k < KDIM; ++k) buf[ch * 1056 + nl * 33 + k] = acc[k];  // bank=nl: clean
    __syncthreads();
    // reduce 8 chunks; 4 outputs/thread; store coalesced float4 ([n][k] layout)
    float v[4];
#pragma unroll
    for (int q = 0; q < 4; ++q) {
      const int f = t * 4 + q, kk = f & 31, nn = f >> 5;
      float s = 0.f;
#pragma unroll
      for (int g = 0; g < 8; ++g) s += buf[g * 1056 + nn * 33 + kk];
      v[q] = s;
    }
    const float4 o = {v[0], v[1], v[2], v[3]};
    reinterpret_cast<float4*>(AtXt + blockIdx.x * 32 * KDIM)[t] = o;
  } else {
    // ---- AtA (4 outputs/thread, global broadcast reads) then 1-wave GJ inverse
    const int i = t >> 3, j0 = (t & 7) * 4;
    float a0 = 0.f, a1 = 0.f, a2 = 0.f, a3 = 0.f;
    for (int m = 0; m < MDIM; ++m) {
      const float ai = A[m * KDIM + i];
      const float4 vj = *reinterpret_cast<const float4*>(A + m * KDIM + j0);
      a0 = fmaf(ai, vj.x, a0);
      a1 = fmaf(ai, vj.y, a1);
      a2 = fmaf(ai, vj.z, a2);
      a3 = fmaf(ai, vj.w, a3);
    }
    {
      const float4 o = {a0, a1, a2, a3};
      reinterpret_cast<float4*>(AtA)[t] = o;  // flat index 4t == i*32+j0
    }
    buf[i * 33 + j0 + 0] = a0;  // padded AtAs for the inverse wave
    buf[i * 33 + j0 + 1] = a1;
    buf[i * 33 + j0 + 2] = a2;
    buf[i * 33 + j0 + 3] = a3;
    __syncthreads();
    if (t < 64) {
      const int r = t & 31;
      float m_[KDIM], g_[KDIM];
#pragma unroll
      for (int c = 0; c < KDIM; ++c) {
        m_[c] = buf[r * 33 + c];  // bank (r+c)%32: conflict-free
        g_[c] = (r == c) ? 1.f : 0.f;
      }
      float myinv = 0.f;
#pragma unroll
      for (int j = 0; j < KDIM; ++j) {
        const float inv = rcp_newton(lane_bcast(m_[j], j));
        const float f = (r != j) ? m_[j] * inv : 0.f;
#pragma unroll
        for (int c = j + 1; c < KDIM; ++c) m_[c] = fmaf(-f, lane_bcast(m_[c], j), m_[c]);
#pragma unroll
        for (int c = 0; c < KDIM; ++c) g_[c] = fmaf(-f, lane_bcast(g_[c], j), g_[c]);
        if (r == j) myinv = inv;
      }
      if (t < 32) {
#pragma unroll
        for (int c = 0; c < KDIM; ++c) Ainv[r * KDIM + c] = myinv * g_[c];
      }
    }
  }
}

// ---------------- per-column NNLS, one wave per column -------------------------
// Lane l owns row r=l&31; hi half mirrors lo so all branches are wave-uniform.
// Round 1 from the all-active init skips the w-matvec entirely: the inactive
// set is empty so viol = 0 regardless of w (exact equivalence). Solver:
// annealed-threshold BPP, hard cap 8 rounds, freeze finisher. Masked solves:
// min(p,q)-pivot dual formulation, wrapped in s_setprio(1) (m191: helps
// independent 1-wave blocks at differing phases).
__global__ __launch_bounds__(64, 2) void nnls_kernel(const float* __restrict__ AtA_g,
                                                     const float* __restrict__ Ainv_g,
                                                     const float* __restrict__ AtXt,
                                                     float* __restrict__ S) {
  const int l = threadIdx.x;
  const int r = l & 31;
  const int n = blockIdx.x;

  const float atb = AtXt[n * KDIM + r];  // coalesced; hi half same line

  // ---- shared AtA row + Ainv row ----
  float ata[KDIM], g[KDIM];
#pragma unroll
  for (int q = 0; q < KDIM / 4; ++q) {
    const float4 v = reinterpret_cast<const float4*>(AtA_g + r * KDIM)[q];
    ata[4 * q + 0] = v.x; ata[4 * q + 1] = v.y; ata[4 * q + 2] = v.z; ata[4 * q + 3] = v.w;
    const float4 u = reinterpret_cast<const float4*>(Ainv_g + r * KDIM)[q];
    g[4 * q + 0] = u.x; g[4 * q + 1] = u.y; g[4 * q + 2] = u.z; g[4 * q + 3] = u.w;
  }

  // ---- y = Ainv @ Atb (unconstrained solution; 4 chains for latency) ----
  float y;
  {
    float s0 = 0.f, s1 = 0.f, s2 = 0.f, s3 = 0.f;
#pragma unroll
    for (int c = 0; c < KDIM; c += 4) {
      s0 = fmaf(g[c + 0], lane_bcast(atb, c + 0), s0);
      s1 = fmaf(g[c + 1], lane_bcast(atb, c + 1), s1);
      s2 = fmaf(g[c + 2], lane_bcast(atb, c + 2), s2);
      s3 = fmaf(g[c + 3], lane_bcast(atb, c + 3), s3);
    }
    y = (s0 + s1) + (s2 + s3);
  }

  // masked solve, min(p,q)-pivot dual formulation (registers + readlane only)
  auto solve_dual = [&](unsigned int Pm) -> float {
    __builtin_amdgcn_s_setprio(1);
    const unsigned int Rm = ~Pm;  // removed set (bits 0..31)
    const int p = __popc(Pm);
    float zret;
    if (p <= 32 - p) {
      // ---- active-set GJ on AtA ----
      const bool actl = (Pm >> r) & 1u;
      float m[KDIM];
#pragma unroll
      for (int c = 0; c < KDIM; ++c)
        m[c] = (actl && ((Pm >> c) & 1u)) ? ata[c] : ((r == c) ? 1.f : 0.f);
      float rhs = actl ? atb : 0.f;
      float myinv = 0.f;
#pragma unroll
      for (int j = 0; j < KDIM; ++j) {
        if ((Pm >> j) & 1u) {
          const float inv = rcp_fast(lane_bcast(m[j], j));
          const float f = (r != j) ? m[j] * inv : 0.f;
#pragma unroll
          for (int c = j + 1; c < KDIM; ++c) m[c] = fmaf(-f, lane_bcast(m[c], j), m[c]);
          rhs = fmaf(-f, lane_bcast(rhs, j), rhs);
          if (r == j) myinv = inv;
        }
      }
      zret = rhs * myinv;  // inactive rows -> exact 0
    } else {
      // ---- removed-set GJ on G = AtA^-1: G_RR u = y_R; z = y - G[:,R] u ----
      const bool reml = (Rm >> r) & 1u;
      float m[KDIM];
#pragma unroll
      for (int c = 0; c < KDIM; ++c)
        m[c] = (reml && ((Rm >> c) & 1u)) ? g[c] : ((r == c) ? 1.f : 0.f);
      float rhs = reml ? y : 0.f;
      float myinv = 0.f;
#pragma unroll
      for (int j = 0; j < KDIM; ++j) {
        if ((Rm >> j) & 1u) {
          const float inv = rcp_fast(lane_bcast(m[j], j));
          const float f = (r != j) ? m[j] * inv : 0.f;
#pragma unroll
          for (int c = j + 1; c < KDIM; ++c) m[c] = fmaf(-f, lane_bcast(m[c], j), m[c]);
          rhs = fmaf(-f, lane_bcast(rhs, j), rhs);
          if (r == j) myinv = inv;
        }
      }
      const float u = rhs * myinv;  // u_c = 0 for c notin R
      float z0 = y, z1 = 0.f, z2 = 0.f, z3 = 0.f;
#pragma unroll
      for (int c = 0; c < KDIM; c += 4) {
        z0 = fmaf(-g[c + 0], lane_bcast(u, c + 0), z0);
        z1 = fmaf(-g[c + 1], lane_bcast(u, c + 1), z1);
        z2 = fmaf(-g[c + 2], lane_bcast(u, c + 2), z2);
        z3 = fmaf(-g[c + 3], lane_bcast(u, c + 3), z3);
      }
      zret = (z0 + z1) + (z2 + z3);  // removed rows -> ~0 (roundoff only)
    }
    __builtin_amdgcn_s_setprio(0);
    return zret;
  };

  // ---- init + round 1 (w-free: inactive set empty => viol = 0 exactly) ----
  unsigned int P = (unsigned int)(__ballot(atb > 1e-6f) & 0xffffffffull);
  float z;
  float zeps = 0.f, weps = W_TOL;
  int best = 1000;
  bool conv = false;
  int it0;
  if (P == 0xffffffffu) {
    z = y;
    const unsigned int u0 = (unsigned int)(__ballot(z < 0.f) & 0xffffffffull);
    if (u0 == 0u) {
      conv = true;
    } else {
      best = __popc(u0);
      P &= ~u0;           // pure removal; dual path (q small) does the solve
      z = solve_dual(P);
    }
    it0 = 1;
  } else {
    z = solve_dual(P);
    it0 = 0;
  }

  // ---- annealed-threshold block principal pivoting, hard cap 8 rounds ----
  for (int it = it0; it < 8 && !conv; ++it) {
    const bool act = (P >> r) & 1u;
    float s0 = 0.f, s1 = 0.f, s2 = 0.f, s3 = 0.f;
#pragma unroll
    for (int c = 0; c < KDIM; c += 4) {
      s0 = fmaf(ata[c + 0], lane_bcast(z, c + 0), s0);
      s1 = fmaf(ata[c + 1], lane_bcast(z, c + 1), s1);
      s2 = fmaf(ata[c + 2], lane_bcast(z, c + 2), s2);
      s3 = fmaf(ata[c + 3], lane_bcast(z, c + 3), s3);
    }
    const float w = atb - ((s0 + s1) + (s2 + s3));
    const bool pred = act ? (z < -zeps) : (w > weps);
    const unsigned int u = (unsigned int)(__ballot(pred) & 0xffffffffull);
    if (u == 0u) { conv = true; break; }  // annealed-KKT satisfied (uniform)
    const int ninf = __popc(u);
    if (ninf < best) {
      best = ninf;
    } else {  // non-improving round: escalate immediately
      zeps = fminf(zeps * 4.f + 2e-6f, 2.5e-4f);
      weps *= 4.f;
    }
    P = (P & ~(u & P)) | (u & ~P);  // block flip: drop bad, add violators
    z = solve_dual(P);
  }

  // ---- freeze finisher for stragglers: drop stubborn negatives, one solve ----
  if (!conv) {
    const unsigned int drop =
        (unsigned int)(__ballot(((P >> r) & 1u) && (z < -2.5e-4f)) & 0xffffffffull);
    if (drop != 0u) {
      P &= ~drop;
      z = solve_dual(P);
    }
  }

  if (l < KDIM) S[r * NDIM + n] = ((P >> r) & 1u) ? fmaxf(z, 0.f) : 0.f;
}

extern "C" void kernel_launch(void* const* d_in, const int* in_sizes, int n_in,
                              void* d_out, int out_size, void* d_ws, size_t ws_size,
                              hipStream_t stream) {
  const float* X = (const float*)d_in[0];  // [256, 2048]
  const float* A = (const float*)d_in[1];  // [256, 32]
  float* S = (float*)d_out;                // [32, 2048]
  float* AtA = (float*)d_ws;               // 1024 floats
  float* Ainv = AtA + KDIM * KDIM;         // 1024 floats
  float* AtXt = Ainv + KDIM * KDIM;        // 65536 floats, [n][k]

  prep_kernel<<<65, 256, 0, stream>>>(A, X, AtA, Ainv, AtXt);
  nnls_kernel<<<NDIM, 64, 0, stream>>>(AtA, Ainv, AtXt, S);
}

// Round 17
// 32.653 us; speedup vs baseline: 1.3264x; 1.3264x over previous
//
#include <hip/hip_runtime.h>
#include <math.h>

#define KDIM 32
#define MDIM 256
#define NDIM 2048
#define W_TOL 1e-3f   // base add threshold (hysteresis; solution shift <= W_TOL/lambda_min ~ 1e-5)

// ---------------- helpers ----------------
__device__ __forceinline__ float lane_bcast(float x, int lane) {
  return __int_as_float(__builtin_amdgcn_readlane(__float_as_int(x), lane));
}
__device__ __forceinline__ float rcp_newton(float x) {
  float r;
  asm("v_rcp_f32 %0, %1" : "=v"(r) : "v"(x));
  r = r * (2.0f - x * r);  // one Newton step (shared inverse only)
  return r;
}
__device__ __forceinline__ float rcp_fast(float x) {
  float r;
  asm("v_rcp_f32 %0, %1" : "=v"(r) : "v"(x));
  return r;  // ~1 ulp; fine vs 3e-3 threshold (kappa ~ 56 both modes)
}

// ---------------- prep: AtXt (blocks 0..63) + AtA & inverse (block 64) ---------
// One launch replaces {ata_partial, inv_kernel, nnls-Atb-prologue}. The serial
// 1-wave GJ inverse runs concurrently with the 64 AtX blocks.
__global__ __launch_bounds__(256) void prep_kernel(const float* __restrict__ A,
                                                   const float* __restrict__ X,
                                                   float* __restrict__ AtA,
                                                   float* __restrict__ Ainv,
                                                   float* __restrict__ AtXt) {
  __shared__ float buf[8448];  // 33 KB: A staging (8192), then reused
  const int t = threadIdx.x;
  // stage A (256x32 = 8192 floats) coalesced: 8 float4 per thread
  {
    const float4* A4 = reinterpret_cast<const float4*>(A);
    float4* B4 = reinterpret_cast<float4*>(buf);
#pragma unroll
    for (int i = 0; i < 8; ++i) B4[t + 256 * i] = A4[t + 256 * i];
  }
  __syncthreads();

  if (blockIdx.x < 64) {
    // ---- AtXt[n][k] for 32 columns; 8-way m-split across 256 threads ----
    const int nl = t & 31;     // column within block
    const int ch = t >> 5;     // m-chunk 0..7
    const int n = blockIdx.x * 32 + nl;
    float acc[KDIM];
#pragma unroll
    for (int k = 0; k < KDIM; ++k) acc[k] = 0.f;
#pragma unroll 4
    for (int mm = 0; mm < 32; ++mm) {
      const int m = ch * 32 + mm;
      const float x = X[m * NDIM + n];  // 2 coalesced 128B segments per instr
#pragma unroll
      for (int qq = 0; qq < 8; ++qq) {
        const float4 a4 = *reinterpret_cast<const float4*>(&buf[m * KDIM + qq * 4]);
        acc[4 * qq + 0] = fmaf(a4.x, x, acc[4 * qq + 0]);  // LDS broadcast reads
        acc[4 * qq + 1] = fmaf(a4.y, x, acc[4 * qq + 1]);
        acc[4 * qq + 2] = fmaf(a4.z, x, acc[4 * qq + 2]);
        acc[4 * qq + 3] = fmaf(a4.w, x, acc[4 * qq + 3]);
      }
    }
    __syncthreads();  // done reading A; reuse buf as red[ch][nl][33]
#pragma unroll
    for (int k = 0; k < KDIM; ++k) buf[ch * 1056 + nl * 33 + k] = acc[k];  // bank = nl: clean
    __syncthreads();
    // reduce 8 chunks; 4 outputs/thread; store coalesced float4 ([n][k] layout)
    float v[4];
#pragma unroll
    for (int q = 0; q < 4; ++q) {
      const int f = t * 4 + q, kk = f & 31, nn = f >> 5;
      float s = 0.f;
#pragma unroll
      for (int g = 0; g < 8; ++g) s += buf[g * 1056 + nn * 33 + kk];
      v[q] = s;
    }
    const float4 o = {v[0], v[1], v[2], v[3]};
    reinterpret_cast<float4*>(AtXt + blockIdx.x * 32 * KDIM)[t] = o;
  } else {
    // ---- AtA (4 outputs/thread, LDS broadcast) then 1-wave GJ inverse ----
    const int i = t >> 3, j0 = (t & 7) * 4;
    float a0 = 0.f, a1 = 0.f, a2 = 0.f, a3 = 0.f;
    for (int m = 0; m < MDIM; ++m) {
      const float ai = buf[m * KDIM + i];
      const float4 vj = *reinterpret_cast<const float4*>(&buf[m * KDIM + j0]);
      a0 = fmaf(ai, vj.x, a0);
      a1 = fmaf(ai, vj.y, a1);
      a2 = fmaf(ai, vj.z, a2);
      a3 = fmaf(ai, vj.w, a3);
    }
    __syncthreads();  // all done reading A
    {
      const float4 o = {a0, a1, a2, a3};
      reinterpret_cast<float4*>(AtA)[t] = o;  // flat index 4t == i*32+j0
    }
    buf[i * 33 + j0 + 0] = a0;  // padded AtAs for the inverse wave
    buf[i * 33 + j0 + 1] = a1;
    buf[i * 33 + j0 + 2] = a2;
    buf[i * 33 + j0 + 3] = a3;
    __syncthreads();
    if (t < 64) {
      const int r = t & 31;
      float m_[KDIM], g_[KDIM];
#pragma unroll
      for (int c = 0; c < KDIM; ++c) {
        m_[c] = buf[r * 33 + c];  // bank (r+c)%32: conflict-free
        g_[c] = (r == c) ? 1.f : 0.f;
      }
      float myinv = 0.f;
#pragma unroll
      for (int j = 0; j < KDIM; ++j) {
        const float inv = rcp_newton(lane_bcast(m_[j], j));
        const float f = (r != j) ? m_[j] * inv : 0.f;
#pragma unroll
        for (int c = j + 1; c < KDIM; ++c) m_[c] = fmaf(-f, lane_bcast(m_[c], j), m_[c]);
#pragma unroll
        for (int c = 0; c < KDIM; ++c) g_[c] = fmaf(-f, lane_bcast(g_[c], j), g_[c]);
        if (r == j) myinv = inv;
      }
      if (t < 32) {
#pragma unroll
        for (int c = 0; c < KDIM; ++c) Ainv[r * KDIM + c] = myinv * g_[c];
      }
    }
  }
}

// ---------------- per-column NNLS, one wave per column -------------------------
// Lane l owns row r=l&31; hi half mirrors lo so all branches are wave-uniform.
// Atb arrives precomputed (one coalesced 128B load). Solver: annealed-threshold
// block principal pivoting, hard cap 8 rounds, then freeze finisher (R14-proven).
// Masked solves: min(p,q)-pivot dual formulation (active-set GJ on AtA, or
// removed-set GJ on G = AtA^-1: z = y - G[:,R] (G_RR)^-1 y_R).
__global__ __launch_bounds__(64, 2) void nnls_kernel(const float* __restrict__ AtA_g,
                                                     const float* __restrict__ Ainv_g,
                                                     const float* __restrict__ AtXt,
                                                     float* __restrict__ S) {
  const int l = threadIdx.x;
  const int r = l & 31;
  const int n = blockIdx.x;

  const float atb = AtXt[n * KDIM + r];  // coalesced; hi half same line

  // ---- shared AtA row + Ainv row ----
  float ata[KDIM], g[KDIM];
#pragma unroll
  for (int q = 0; q < KDIM / 4; ++q) {
    const float4 v = reinterpret_cast<const float4*>(AtA_g + r * KDIM)[q];
    ata[4 * q + 0] = v.x; ata[4 * q + 1] = v.y; ata[4 * q + 2] = v.z; ata[4 * q + 3] = v.w;
    const float4 u = reinterpret_cast<const float4*>(Ainv_g + r * KDIM)[q];
    g[4 * q + 0] = u.x; g[4 * q + 1] = u.y; g[4 * q + 2] = u.z; g[4 * q + 3] = u.w;
  }

  // ---- y = Ainv @ Atb (unconstrained solution; 4 chains for latency) ----
  float y;
  {
    float s0 = 0.f, s1 = 0.f, s2 = 0.f, s3 = 0.f;
#pragma unroll
    for (int c = 0; c < KDIM; c += 4) {
      s0 = fmaf(g[c + 0], lane_bcast(atb, c + 0), s0);
      s1 = fmaf(g[c + 1], lane_bcast(atb, c + 1), s1);
      s2 = fmaf(g[c + 2], lane_bcast(atb, c + 2), s2);
      s3 = fmaf(g[c + 3], lane_bcast(atb, c + 3), s3);
    }
    y = (s0 + s1) + (s2 + s3);
  }

  // masked solve, min(p,q)-pivot dual formulation (registers + readlane only)
  auto solve_dual = [&](unsigned int Pm) -> float {
    const unsigned int Rm = ~Pm;  // removed set (bits 0..31)
    const int p = __popc(Pm);
    if (p <= 32 - p) {
      // ---- active-set GJ on AtA ----
      const bool actl = (Pm >> r) & 1u;
      float m[KDIM];
#pragma unroll
      for (int c = 0; c < KDIM; ++c)
        m[c] = (actl && ((Pm >> c) & 1u)) ? ata[c] : ((r == c) ? 1.f : 0.f);
      float rhs = actl ? atb : 0.f;
      float myinv = 0.f;
#pragma unroll
      for (int j = 0; j < KDIM; ++j) {
        if ((Pm >> j) & 1u) {
          const float inv = rcp_fast(lane_bcast(m[j], j));
          const float f = (r != j) ? m[j] * inv : 0.f;
#pragma unroll
          for (int c = j + 1; c < KDIM; ++c) m[c] = fmaf(-f, lane_bcast(m[c], j), m[c]);
          rhs = fmaf(-f, lane_bcast(rhs, j), rhs);
          if (r == j) myinv = inv;
        }
      }
      return rhs * myinv;  // inactive rows -> exact 0
    } else {
      // ---- removed-set GJ on G = AtA^-1: G_RR u = y_R; z = y - G[:,R] u ----
      const bool reml = (Rm >> r) & 1u;
      float m[KDIM];
#pragma unroll
      for (int c = 0; c < KDIM; ++c)
        m[c] = (reml && ((Rm >> c) & 1u)) ? g[c] : ((r == c) ? 1.f : 0.f);
      float rhs = reml ? y : 0.f;
      float myinv = 0.f;
#pragma unroll
      for (int j = 0; j < KDIM; ++j) {
        if ((Rm >> j) & 1u) {
          const float inv = rcp_fast(lane_bcast(m[j], j));
          const float f = (r != j) ? m[j] * inv : 0.f;
#pragma unroll
          for (int c = j + 1; c < KDIM; ++c) m[c] = fmaf(-f, lane_bcast(m[c], j), m[c]);
          rhs = fmaf(-f, lane_bcast(rhs, j), rhs);
          if (r == j) myinv = inv;
        }
      }
      const float u = rhs * myinv;  // u_c = 0 for c notin R
      float z0 = y, z1 = 0.f, z2 = 0.f, z3 = 0.f;
#pragma unroll
      for (int c = 0; c < KDIM; c += 4) {
        z0 = fmaf(-g[c + 0], lane_bcast(u, c + 0), z0);
        z1 = fmaf(-g[c + 1], lane_bcast(u, c + 1), z1);
        z2 = fmaf(-g[c + 2], lane_bcast(u, c + 2), z2);
        z3 = fmaf(-g[c + 3], lane_bcast(u, c + 3), z3);
      }
      return (z0 + z1) + (z2 + z3);  // removed rows -> ~0 (roundoff only)
    }
  };

  // ---- init ----
  unsigned int P = (unsigned int)(__ballot(atb > 1e-6f) & 0xffffffffull);
  float z = (P == 0xffffffffu) ? y : solve_dual(P);

  // ---- annealed-threshold block principal pivoting, hard cap 8 rounds ----
  float zeps = 0.f, weps = W_TOL;
  int best = 1000;
  bool conv = false;
  for (int it = 0; it < 8; ++it) {
    const bool act = (P >> r) & 1u;
    float s0 = 0.f, s1 = 0.f, s2 = 0.f, s3 = 0.f;
#pragma unroll
    for (int c = 0; c < KDIM; c += 4) {
      s0 = fmaf(ata[c + 0], lane_bcast(z, c + 0), s0);
      s1 = fmaf(ata[c + 1], lane_bcast(z, c + 1), s1);
      s2 = fmaf(ata[c + 2], lane_bcast(z, c + 2), s2);
      s3 = fmaf(ata[c + 3], lane_bcast(z, c + 3), s3);
    }
    const float w = atb - ((s0 + s1) + (s2 + s3));
    const bool pred = act ? (z < -zeps) : (w > weps);
    const unsigned int u = (unsigned int)(__ballot(pred) & 0xffffffffull);
    if (u == 0u) { conv = true; break; }  // annealed-KKT satisfied (uniform)
    const int ninf = __popc(u);
    if (ninf < best) {
      best = ninf;
    } else {  // non-improving round: escalate immediately
      zeps = fminf(zeps * 4.f + 2e-6f, 2.5e-4f);
      weps *= 4.f;
    }
    P = (P & ~(u & P)) | (u & ~P);  // block flip: drop bad, add violators
    z = solve_dual(P);
  }

  // ---- freeze finisher for stragglers: drop stubborn negatives, one solve ----
  if (!conv) {
    const unsigned int drop =
        (unsigned int)(__ballot(((P >> r) & 1u) && (z < -2.5e-4f)) & 0xffffffffull);
    if (drop != 0u) {
      P &= ~drop;
      z = solve_dual(P);
    }
  }

  if (l < KDIM) S[r * NDIM + n] = ((P >> r) & 1u) ? fmaxf(z, 0.f) : 0.f;
}

extern "C" void kernel_launch(void* const* d_in, const int* in_sizes, int n_in,
                              void* d_out, int out_size, void* d_ws, size_t ws_size,
                              hipStream_t stream) {
  const float* X = (const float*)d_in[0];  // [256, 2048]
  const float* A = (const float*)d_in[1];  // [256, 32]
  float* S = (float*)d_out;                // [32, 2048]
  float* AtA = (float*)d_ws;               // 1024 floats
  float* Ainv = AtA + KDIM * KDIM;         // 1024 floats
  float* AtXt = Ainv + KDIM * KDIM;        // 65536 floats, [n][k]

  prep_kernel<<<65, 256, 0, stream>>>(A, X, AtA, Ainv, AtXt);
  nnls_kernel<<<NDIM, 64, 0, stream>>>(AtA, Ainv, AtXt, S);
}